// Round 9
// baseline (50.084 us; speedup 1.0000x reference)
//
#include <hip/hip_runtime.h>

#define D   512
#define HW  196   // 14*14
#define NS  8     // K-split count for the small GEMMs
#define MS  16    // k-split count for the KB passes

// Workspace layout (floats):
//   p_part   [NS][128][512]   @ 0        (524288)
//   t12_part [NS][128][1024]  @ 524288   (1048576)
//   mvp      [128][MS][196]   @ 1572864  (401408)

// ---------------------------------------------------------------------------
// K1 (384 blocks): blocks 0..127 -> p partials, 128..383 -> t12 partials.
// (R5-proven structure, unchanged.)
// ---------------------------------------------------------------------------
__global__ void k_stage1(const float* __restrict__ m_prev, const float* __restrict__ W_m,
                         const float* __restrict__ b_m, const float* __restrict__ c,
                         const float* __restrict__ W_attn, const float* __restrict__ W_merge,
                         float* __restrict__ p_part, float* __restrict__ t12_part) {
    const int bx = blockIdx.x;
    const int t  = threadIdx.x;
    __shared__ float xs[16][64];

    if (bx < 128) {                       // ---- p: (jt2, bt8, kt8) ----
        const int jt = bx & 1, bt = (bx >> 1) & 7, kt = bx >> 4;
        const int j  = jt * 256 + t;
        const int b0 = bt * 16;
        const int k0 = kt * 64;
        for (int i = t; i < 16 * 64; i += 256)
            xs[i >> 6][i & 63] = m_prev[(b0 + (i >> 6)) * D + k0 + (i & 63)];
        __syncthreads();
        float acc[16];
        #pragma unroll
        for (int bb = 0; bb < 16; ++bb) acc[bb] = 0.f;
        for (int kk = 0; kk < 64; ++kk) {
            float wv = W_m[(k0 + kk) * D + j];        // coalesced across lanes
            #pragma unroll
            for (int bb = 0; bb < 16; ++bb) acc[bb] += xs[bb][kk] * wv;
        }
        const float bias = (kt == 0) ? b_m[j] : 0.f;  // bias folded into split 0
        #pragma unroll
        for (int bb = 0; bb < 16; ++bb)
            p_part[((size_t)kt * 128 + b0 + bb) * D + j] = acc[bb] + bias;
    } else {                              // ---- t12: (kkt4, bt8, jt8) ----
        const int i2 = bx - 128;
        const int kkt = i2 & 3, bt = (i2 >> 2) & 7, jt = i2 >> 5;
        const int kk = kkt * 256 + t;     // 0..1023
        const int b0 = bt * 16;
        const int j0 = jt * 64;
        for (int i = t; i < 16 * 64; i += 256) {
            int bb = i >> 6, jj = i & 63;
            xs[bb][jj] = c[(b0 + bb) * D + j0 + jj] * W_attn[j0 + jj];
        }
        __syncthreads();
        float acc[16];
        #pragma unroll
        for (int bb = 0; bb < 16; ++bb) acc[bb] = 0.f;
        const float4* wrow = (const float4*)&W_merge[(size_t)kk * D + j0];
        for (int q = 0; q < 16; ++q) {
            float4 w4 = wrow[q];
            #pragma unroll
            for (int bb = 0; bb < 16; ++bb)
                acc[bb] += xs[bb][4*q+0] * w4.x + xs[bb][4*q+1] * w4.y
                         + xs[bb][4*q+2] * w4.z + xs[bb][4*q+3] * w4.w;
        }
        #pragma unroll
        for (int bb = 0; bb < 16; ++bb)
            t12_part[((size_t)jt * 128 + b0 + bb) * 1024 + kk] = acc[bb];
    }
}

// ---------------------------------------------------------------------------
// K2 (2048 blocks (b, ks), 256 threads): fused w-chunk + beta + mv.
//   KB chunk loads issued FIRST into registers (independent of everything),
//   so the HBM stream runs under the fold/GEMM/shfl latency.  (G7)
// ---------------------------------------------------------------------------
__global__ __launch_bounds__(256, 4)
void k_wmv(const float* __restrict__ KB, const float* __restrict__ p_part,
           const float* __restrict__ t12_part, const float* __restrict__ W_kb,
           const float* __restrict__ c, const float* __restrict__ W_attn,
           const float* __restrict__ b_merge, const float* __restrict__ b_kb,
           const float* __restrict__ b_attn, float* __restrict__ mvp) {
    const int b    = blockIdx.x >> 4;
    const int ks   = blockIdx.x & (MS - 1);
    const int t    = threadIdx.x;
    const int wave = t >> 6, lane = t & 63;

    __shared__ float r_s[512];
    __shared__ float wl[32];
    __shared__ float winit[32];
    __shared__ float redB[4];

    // ---- prefetch: issue the 32 KB loads for this chunk NOW ----
    float kbreg[32];
    if (t < HW) {
        const float* kbp = KB + (size_t)b * D * HW + (size_t)ks * 32 * HW + t;
        #pragma unroll
        for (int k = 0; k < 32; ++k) kbreg[k] = kbp[(size_t)k * HW];
    }

    // ---- step 1: fold r and t2-chunk (coalesced) ----
    for (int k = t; k < 512; k += 256) {
        float pv = 0.f, tv = 0.f;
        #pragma unroll
        for (int s = 0; s < NS; ++s) {
            pv += p_part[((size_t)s * 128 + b) * D + k];
            tv += t12_part[((size_t)s * 128 + b) * 1024 + k];   // t1 = cols [0,512)
        }
        r_s[k] = pv * tv;
    }
    if (t < 32) {
        float s2 = 0.f;
        #pragma unroll
        for (int s = 0; s < NS; ++s)
            s2 += t12_part[((size_t)s * 128 + b) * 1024 + 512 + ks * 32 + t];
        winit[t] = s2;
    }
    __syncthreads();

    // ---- beta (ks==0 blocks only) ----
    if (ks == 0) {
        float bsum = 0.f;
        for (int k = t; k < 512; k += 256)
            bsum += b_merge[k] * c[(size_t)b * D + k] * W_attn[k] + b_kb[k] * r_s[k];
        #pragma unroll
        for (int off = 32; off; off >>= 1) bsum += __shfl_down(bsum, off, 64);
        if (lane == 0) redB[wave] = bsum;
    }

    // ---- step 2: w rows (wave-per-row; r-fragment hoisted to registers) ----
    const float4 ra = *(const float4*)&r_s[lane * 8];
    const float4 rb = *(const float4*)&r_s[lane * 8 + 4];
    #pragma unroll
    for (int i = 0; i < 8; ++i) {
        const int row = ks * 32 + wave * 8 + i;
        const float4* wr = (const float4*)&W_kb[(size_t)row * D + lane * 8];
        float4 w0 = wr[0], w1 = wr[1];
        float dot = w0.x * ra.x + w0.y * ra.y + w0.z * ra.z + w0.w * ra.w
                  + w1.x * rb.x + w1.y * rb.y + w1.z * rb.z + w1.w * rb.w;
        #pragma unroll
        for (int off = 32; off; off >>= 1) dot += __shfl_down(dot, off, 64);
        if (lane == 0) wl[wave * 8 + i] = dot + winit[wave * 8 + i];
    }
    __syncthreads();

    // ---- step 3: mv chunk from prefetched registers ----
    float beta = 0.f;
    if (ks == 0) beta = redB[0] + redB[1] + redB[2] + redB[3] + b_attn[0];
    if (t < HW) {
        float acc = beta;
        #pragma unroll
        for (int k = 0; k < 32; ++k) acc += kbreg[k] * wl[k];
        mvp[((size_t)b * MS + ks) * HW + t] = acc;
    }
}

// ---------------------------------------------------------------------------
// K3 (2048 blocks (b, kt), 256 threads = 4 waves x 8 rows): out pass.
// KB row float4s prefetched into registers before the mvp fold, so the
// (L3-served) row stream overlaps the fold latency.
// ---------------------------------------------------------------------------
__global__ void k_mnew(const float* __restrict__ KB, const float* __restrict__ mvp,
                       float* __restrict__ out) {
    const int b  = blockIdx.x >> 4;
    const int kt = blockIdx.x & 15;
    const int t  = threadIdx.x;
    const int wave = t >> 6, lane = t & 63;
    __shared__ float4 mv4_s[49];

    // ---- prefetch the 8 row-fragments this lane will dot ----
    float4 v[8];
    if (lane < 49) {
        #pragma unroll
        for (int i = 0; i < 8; ++i) {
            const int k = kt * 32 + wave * 8 + i;
            v[i] = ((const float4*)(KB + ((size_t)b * D + k) * HW))[lane];
        }
    }

    // ---- fold mvp partials (beta already included) into LDS ----
    if (t < HW) {
        float s = 0.f;
        #pragma unroll
        for (int q = 0; q < MS; ++q)
            s += mvp[((size_t)b * MS + q) * HW + t];
        ((float*)mv4_s)[t] = s;
    }
    __syncthreads();

    const float4 m4 = (lane < 49) ? mv4_s[lane] : make_float4(0.f, 0.f, 0.f, 0.f);
    #pragma unroll
    for (int i = 0; i < 8; ++i) {
        const int k = kt * 32 + wave * 8 + i;
        float p = 0.f;
        if (lane < 49)
            p = v[i].x * m4.x + v[i].y * m4.y + v[i].z * m4.z + v[i].w * m4.w;
        #pragma unroll
        for (int off = 32; off; off >>= 1) p += __shfl_xor(p, off, 64);
        if (lane == 0) out[(size_t)b * D + k] = p;
    }
}

// ---------------------------------------------------------------------------
extern "C" void kernel_launch(void* const* d_in, const int* in_sizes, int n_in,
                              void* d_out, int out_size, void* d_ws, size_t ws_size,
                              hipStream_t stream) {
    const float* m_prev  = (const float*)d_in[0];
    const float* KB      = (const float*)d_in[1];
    const float* c_i     = (const float*)d_in[2];
    const float* W_m     = (const float*)d_in[3];
    const float* b_m     = (const float*)d_in[4];
    const float* W_kb    = (const float*)d_in[5];
    const float* b_kb    = (const float*)d_in[6];
    const float* W_merge = (const float*)d_in[7];
    const float* b_merge = (const float*)d_in[8];
    const float* W_attn  = (const float*)d_in[9];
    const float* b_attn  = (const float*)d_in[10];
    float* out = (float*)d_out;

    float* ws       = (float*)d_ws;
    float* p_part   = ws;               // [NS][128][512]
    float* t12_part = ws + 524288;      // [NS][128][1024]
    float* mvp      = ws + 1572864;     // [128][MS][196]

    k_stage1<<<384, 256, 0, stream>>>(m_prev, W_m, b_m, c_i, W_attn, W_merge,
                                      p_part, t12_part);
    k_wmv  <<<2048, 256, 0, stream>>>(KB, p_part, t12_part, W_kb, c_i, W_attn,
                                      b_merge, b_kb, b_attn, mvp);
    k_mnew <<<2048, 256, 0, stream>>>(KB, mvp, out);
}

// Round 10
// 45.147 us; speedup vs baseline: 1.1094x; 1.1094x over previous
//
#include <hip/hip_runtime.h>

#define D   512
#define HW  196   // 14*14
#define NS  8     // K-split count for the small GEMMs
#define MS  16    // k-split count for the KB passes

// Workspace layout (floats):
//   p_part   [NS][128][512]   @ 0        (524288)
//   t12_part [NS][128][1024]  @ 524288   (1048576)
//   mvp      [128][MS][196]   @ 1572864  (401408)

// ---------------------------------------------------------------------------
// K1 (384 blocks): blocks 0..127 -> p partials, 128..383 -> t12 partials.
// (R5/R8-proven structure, unchanged.)
// ---------------------------------------------------------------------------
__global__ void k_stage1(const float* __restrict__ m_prev, const float* __restrict__ W_m,
                         const float* __restrict__ b_m, const float* __restrict__ c,
                         const float* __restrict__ W_attn, const float* __restrict__ W_merge,
                         float* __restrict__ p_part, float* __restrict__ t12_part) {
    const int bx = blockIdx.x;
    const int t  = threadIdx.x;
    __shared__ float xs[16][64];

    if (bx < 128) {                       // ---- p: (jt2, bt8, kt8) ----
        const int jt = bx & 1, bt = (bx >> 1) & 7, kt = bx >> 4;
        const int j  = jt * 256 + t;
        const int b0 = bt * 16;
        const int k0 = kt * 64;
        for (int i = t; i < 16 * 64; i += 256)
            xs[i >> 6][i & 63] = m_prev[(b0 + (i >> 6)) * D + k0 + (i & 63)];
        __syncthreads();
        float acc[16];
        #pragma unroll
        for (int bb = 0; bb < 16; ++bb) acc[bb] = 0.f;
        for (int kk = 0; kk < 64; ++kk) {
            float wv = W_m[(k0 + kk) * D + j];        // coalesced across lanes
            #pragma unroll
            for (int bb = 0; bb < 16; ++bb) acc[bb] += xs[bb][kk] * wv;
        }
        const float bias = (kt == 0) ? b_m[j] : 0.f;  // bias folded into split 0
        #pragma unroll
        for (int bb = 0; bb < 16; ++bb)
            p_part[((size_t)kt * 128 + b0 + bb) * D + j] = acc[bb] + bias;
    } else {                              // ---- t12: (kkt4, bt8, jt8) ----
        const int i2 = bx - 128;
        const int kkt = i2 & 3, bt = (i2 >> 2) & 7, jt = i2 >> 5;
        const int kk = kkt * 256 + t;     // 0..1023
        const int b0 = bt * 16;
        const int j0 = jt * 64;
        for (int i = t; i < 16 * 64; i += 256) {
            int bb = i >> 6, jj = i & 63;
            xs[bb][jj] = c[(b0 + bb) * D + j0 + jj] * W_attn[j0 + jj];
        }
        __syncthreads();
        float acc[16];
        #pragma unroll
        for (int bb = 0; bb < 16; ++bb) acc[bb] = 0.f;
        const float4* wrow = (const float4*)&W_merge[(size_t)kk * D + j0];
        for (int q = 0; q < 16; ++q) {
            float4 w4 = wrow[q];
            #pragma unroll
            for (int bb = 0; bb < 16; ++bb)
                acc[bb] += xs[bb][4*q+0] * w4.x + xs[bb][4*q+1] * w4.y
                         + xs[bb][4*q+2] * w4.z + xs[bb][4*q+3] * w4.w;
        }
        #pragma unroll
        for (int bb = 0; bb < 16; ++bb)
            t12_part[((size_t)jt * 128 + b0 + bb) * 1024 + kk] = acc[bb];
    }
}

// ---------------------------------------------------------------------------
// K2 (1024 blocks (b-pair, ks), 256 threads): fused w-chunk + beta + mv for
// TWO batches per block — each W_kb row fragment is loaded once and dotted
// against both r vectors (halves W_kb L2 traffic: 128 MB -> 64 MB).
// ---------------------------------------------------------------------------
__global__ __launch_bounds__(256, 4)
void k_wmv(const float* __restrict__ KB, const float* __restrict__ p_part,
           const float* __restrict__ t12_part, const float* __restrict__ W_kb,
           const float* __restrict__ c, const float* __restrict__ W_attn,
           const float* __restrict__ b_merge, const float* __restrict__ b_kb,
           const float* __restrict__ b_attn, float* __restrict__ mvp) {
    const int b2   = blockIdx.x >> 4;          // 0..63  (pair index)
    const int ks   = blockIdx.x & (MS - 1);    // 0..15
    const int b0   = b2 * 2;                   // first batch of the pair
    const int t    = threadIdx.x;
    const int wave = t >> 6, lane = t & 63;

    __shared__ float r_s[2][512];
    __shared__ float wl[2][32];
    __shared__ float winit[2][32];
    __shared__ float redB[4];

    // ---- step 1: fold r for both batches (coalesced) ----
    for (int i = t; i < 1024; i += 256) {
        const int bb = i >> 9, k = i & 511;
        const int b = b0 + bb;
        float pv = 0.f, tv = 0.f;
        #pragma unroll
        for (int s = 0; s < NS; ++s) {
            pv += p_part[((size_t)s * 128 + b) * D + k];
            tv += t12_part[((size_t)s * 128 + b) * 1024 + k];   // t1 = cols [0,512)
        }
        r_s[bb][k] = pv * tv;
    }
    if (t < 64) {
        const int bb = t >> 5, idx = t & 31;
        float s2 = 0.f;
        #pragma unroll
        for (int s = 0; s < NS; ++s)
            s2 += t12_part[((size_t)s * 128 + b0 + bb) * 1024 + 512 + ks * 32 + idx];
        winit[bb][idx] = s2;
    }
    __syncthreads();

    // ---- beta (ks==0 blocks only): waves 0-1 -> b0, waves 2-3 -> b1 ----
    if (ks == 0) {
        const int bb = t >> 7;            // 0 or 1
        const int tt = t & 127;
        const int b  = b0 + bb;
        float bsum = 0.f;
        #pragma unroll
        for (int i = 0; i < 4; ++i) {
            const int k = tt + i * 128;
            bsum += b_merge[k] * c[(size_t)b * D + k] * W_attn[k] + b_kb[k] * r_s[bb][k];
        }
        #pragma unroll
        for (int off = 32; off; off >>= 1) bsum += __shfl_down(bsum, off, 64);
        if (lane == 0) redB[wave] = bsum; // waves 0,1 -> b0; 2,3 -> b1
    }

    // ---- step 2: w rows; one W_kb load feeds two dots ----
    const float4 ra0 = *(const float4*)&r_s[0][lane * 8];
    const float4 rb0 = *(const float4*)&r_s[0][lane * 8 + 4];
    const float4 ra1 = *(const float4*)&r_s[1][lane * 8];
    const float4 rb1 = *(const float4*)&r_s[1][lane * 8 + 4];
    #pragma unroll
    for (int i = 0; i < 8; ++i) {
        const int rr  = wave * 8 + i;
        const int row = ks * 32 + rr;
        const float4* wr = (const float4*)&W_kb[(size_t)row * D + lane * 8];
        float4 w0 = wr[0], w1 = wr[1];
        float d0 = w0.x * ra0.x + w0.y * ra0.y + w0.z * ra0.z + w0.w * ra0.w
                 + w1.x * rb0.x + w1.y * rb0.y + w1.z * rb0.z + w1.w * rb0.w;
        float d1 = w0.x * ra1.x + w0.y * ra1.y + w0.z * ra1.z + w0.w * ra1.w
                 + w1.x * rb1.x + w1.y * rb1.y + w1.z * rb1.z + w1.w * rb1.w;
        #pragma unroll
        for (int off = 32; off; off >>= 1) {
            d0 += __shfl_down(d0, off, 64);
            d1 += __shfl_down(d1, off, 64);
        }
        if (lane == 0) {
            wl[0][rr] = d0 + winit[0][rr];
            wl[1][rr] = d1 + winit[1][rr];
        }
    }
    __syncthreads();

    // ---- step 3: mv chunk for both batches (compiler-scheduled loads) ----
    float beta0 = 0.f, beta1 = 0.f;
    if (ks == 0) {
        beta0 = redB[0] + redB[1] + b_attn[0];
        beta1 = redB[2] + redB[3] + b_attn[0];
    }
    if (t < HW) {
        const float* kbp0 = KB + ((size_t)b0 * D + ks * 32) * HW + t;
        const float* kbp1 = kbp0 + (size_t)D * HW;
        float acc0 = beta0, acc1 = beta1;
        #pragma unroll
        for (int k = 0; k < 32; ++k) {
            acc0 += kbp0[(size_t)k * HW] * wl[0][k];
            acc1 += kbp1[(size_t)k * HW] * wl[1][k];
        }
        mvp[((size_t)b0 * MS + ks) * HW + t] = acc0;
        mvp[(((size_t)b0 + 1) * MS + ks) * HW + t] = acc1;
    }
}

// ---------------------------------------------------------------------------
// K3 (2048 blocks (b, kt), 256 threads = 4 waves x 8 rows): out pass.
// (R8-proven form — no register prefetch.)
// ---------------------------------------------------------------------------
__global__ void k_mnew(const float* __restrict__ KB, const float* __restrict__ mvp,
                       float* __restrict__ out) {
    const int b  = blockIdx.x >> 4;
    const int kt = blockIdx.x & 15;
    const int t  = threadIdx.x;
    const int wave = t >> 6, lane = t & 63;
    __shared__ float4 mv4_s[49];

    if (t < HW) {
        float s = 0.f;
        #pragma unroll
        for (int q = 0; q < MS; ++q)
            s += mvp[((size_t)b * MS + q) * HW + t];
        ((float*)mv4_s)[t] = s;
    }
    __syncthreads();

    const float4 m4 = (lane < 49) ? mv4_s[lane] : make_float4(0.f, 0.f, 0.f, 0.f);
    #pragma unroll
    for (int i = 0; i < 8; ++i) {
        const int k = kt * 32 + wave * 8 + i;
        float p = 0.f;
        if (lane < 49) {
            float4 v = ((const float4*)(KB + ((size_t)b * D + k) * HW))[lane];
            p = v.x * m4.x + v.y * m4.y + v.z * m4.z + v.w * m4.w;
        }
        #pragma unroll
        for (int off = 32; off; off >>= 1) p += __shfl_xor(p, off, 64);
        if (lane == 0) out[(size_t)b * D + k] = p;
    }
}

// ---------------------------------------------------------------------------
extern "C" void kernel_launch(void* const* d_in, const int* in_sizes, int n_in,
                              void* d_out, int out_size, void* d_ws, size_t ws_size,
                              hipStream_t stream) {
    const float* m_prev  = (const float*)d_in[0];
    const float* KB      = (const float*)d_in[1];
    const float* c_i     = (const float*)d_in[2];
    const float* W_m     = (const float*)d_in[3];
    const float* b_m     = (const float*)d_in[4];
    const float* W_kb    = (const float*)d_in[5];
    const float* b_kb    = (const float*)d_in[6];
    const float* W_merge = (const float*)d_in[7];
    const float* b_merge = (const float*)d_in[8];
    const float* W_attn  = (const float*)d_in[9];
    const float* b_attn  = (const float*)d_in[10];
    float* out = (float*)d_out;

    float* ws       = (float*)d_ws;
    float* p_part   = ws;               // [NS][128][512]
    float* t12_part = ws + 524288;      // [NS][128][1024]
    float* mvp      = ws + 1572864;     // [128][MS][196]

    k_stage1<<<384, 256, 0, stream>>>(m_prev, W_m, b_m, c_i, W_attn, W_merge,
                                      p_part, t12_part);
    k_wmv  <<<1024, 256, 0, stream>>>(KB, p_part, t12_part, W_kb, c_i, W_attn,
                                      b_merge, b_kb, b_attn, mvp);
    k_mnew <<<2048, 256, 0, stream>>>(KB, mvp, out);
}